// Round 1
// baseline (1178.928 us; speedup 1.0000x reference)
//
#include <hip/hip_runtime.h>
#include <hip/hip_bf16.h>

// DifferentialAttention: B=2, L=2048, D=1024, H=16, dh=64, scale = D^-0.5 = 1/32.
// Key reduction: a2 = softmax(s_prev) is a column permutation of a1 = softmax(s_cur)
// (k_prev = roll(k,1) permutes score columns; softmax is permutation-equivariant).
//   o = lam * sum_j a1[q,j] * (v[j] - v[(j+1) mod L])
// => ONE softmax, ONE PV matmul against vd = v - roll(v,-1). Flash-style, no S materialized.

#define TILE 64
#define BK 16

// C[m,n] = sum_k A[m,k]*Bm[n,k] + bias[n]   (both operands K-major, "NT" GEMM)
__global__ __launch_bounds__(256) void gemm_nt_bias(
    const float* __restrict__ A,
    const float* __restrict__ Bm,
    const float* __restrict__ bias,
    float* __restrict__ C,
    int M, int N, int K)
{
    __shared__ float As[BK][TILE + 4];   // stored transposed: As[k][m], pad 4 -> conflict-free
    __shared__ float Bs[BK][TILE + 4];
    const int tid = threadIdx.x;
    const int tx = tid & 15, ty = tid >> 4;
    const int m0 = blockIdx.y * TILE, n0 = blockIdx.x * TILE;

    float acc[4][4] = {};

    for (int k0 = 0; k0 < K; k0 += BK) {
#pragma unroll
        for (int i = 0; i < 4; ++i) {
            int idx = tid + i * 256;
            int ml = idx >> 4, kl = idx & 15;
            As[kl][ml] = A[(size_t)(m0 + ml) * K + k0 + kl];
            Bs[kl][ml] = Bm[(size_t)(n0 + ml) * K + k0 + kl];
        }
        __syncthreads();
#pragma unroll
        for (int kk = 0; kk < BK; ++kk) {
            const float4 av = *(const float4*)&As[kk][ty * 4];
            const float4 bv = *(const float4*)&Bs[kk][tx * 4];
            const float a4[4] = {av.x, av.y, av.z, av.w};
            const float b4[4] = {bv.x, bv.y, bv.z, bv.w};
#pragma unroll
            for (int i = 0; i < 4; ++i)
#pragma unroll
                for (int j = 0; j < 4; ++j)
                    acc[i][j] = fmaf(a4[i], b4[j], acc[i][j]);
        }
        __syncthreads();
    }

    const float4 bv = *(const float4*)&bias[n0 + tx * 4];
    const float bb[4] = {bv.x, bv.y, bv.z, bv.w};
#pragma unroll
    for (int i = 0; i < 4; ++i) {
        int m = m0 + ty * 4 + i;
        float4 o;
        o.x = acc[i][0] + bb[0];
        o.y = acc[i][1] + bb[1];
        o.z = acc[i][2] + bb[2];
        o.w = acc[i][3] + bb[3];
        *(float4*)&C[(size_t)m * N + n0 + tx * 4] = o;
    }
}

// One block per (b,h, 64-row q-tile). 256 threads, thread (ty,tx) owns a 4x4
// micro-tile of S/P (rows ty*4.., cols tx*4..) and O (rows ty*4.., dh-cols tx*4..).
__global__ __launch_bounds__(256) void diff_attn(
    const float* __restrict__ qkv,   // [B*L, 3*1024], n = which*1024 + h*64 + c
    const float* __restrict__ lam_p,
    float* __restrict__ o_ws)        // [B*L, 1024]
{
    constexpr int L = 2048;
    constexpr int TD = 3072;
    constexpr float scale = 0.03125f;   // 1024^-0.5

    __shared__ float Qs[64][68];
    __shared__ float KPs[64][68];   // K tile, reused as P tile after S is computed
    __shared__ float Vs[64][68];    // vd tile = v[j] - v[(j+1) mod L]

    const int tid = threadIdx.x;
    const int tx = tid & 15, ty = tid >> 4;
    const int bh = blockIdx.y;
    const int b = bh >> 4, h = bh & 15;
    const int q0 = blockIdx.x * 64;
    const float* base = qkv + (size_t)b * L * TD + h * 64;

    // Q tile -> LDS (coalesced float4)
#pragma unroll
    for (int i = 0; i < 4; ++i) {
        int idx = tid + i * 256;
        int row = idx >> 4, c4 = (idx & 15) * 4;
        *(float4*)&Qs[row][c4] = *(const float4*)(base + (size_t)(q0 + row) * TD + c4);
    }

    float mrow[4], lrow[4];
    float4 O4[4];
#pragma unroll
    for (int i = 0; i < 4; ++i) {
        mrow[i] = -INFINITY; lrow[i] = 0.f;
        O4[i] = make_float4(0.f, 0.f, 0.f, 0.f);
    }

    for (int kt = 0; kt < 32; ++kt) {
        const int j0 = kt * 64;
#pragma unroll
        for (int i = 0; i < 4; ++i) {
            int idx = tid + i * 256;
            int row = idx >> 4, c4 = (idx & 15) * 4;
            int jj = j0 + row;
            *(float4*)&KPs[row][c4] = *(const float4*)(base + 1024 + (size_t)jj * TD + c4);
            float4 v0 = *(const float4*)(base + 2048 + (size_t)jj * TD + c4);
            int jn = (jj + 1) & (L - 1);   // roll within the sequence (same b)
            float4 v1 = *(const float4*)(base + 2048 + (size_t)jn * TD + c4);
            *(float4*)&Vs[row][c4] = make_float4(v0.x - v1.x, v0.y - v1.y,
                                                 v0.z - v1.z, v0.w - v1.w);
        }
        __syncthreads();

        // S micro-tile: 4x4, dot over dh=64 via float4 LDS reads
        float s[4][4] = {};
#pragma unroll
        for (int c4 = 0; c4 < 16; ++c4) {
            float4 qa[4], kb[4];
#pragma unroll
            for (int i = 0; i < 4; ++i) qa[i] = *(const float4*)&Qs[ty * 4 + i][c4 * 4];
#pragma unroll
            for (int j = 0; j < 4; ++j) kb[j] = *(const float4*)&KPs[tx * 4 + j][c4 * 4];
#pragma unroll
            for (int i = 0; i < 4; ++i)
#pragma unroll
                for (int j = 0; j < 4; ++j)
                    s[i][j] = fmaf(qa[i].x, kb[j].x,
                              fmaf(qa[i].y, kb[j].y,
                              fmaf(qa[i].z, kb[j].z,
                              fmaf(qa[i].w, kb[j].w, s[i][j]))));
        }

        // online softmax update; row stats shared across the 16 tx lanes (in-wave)
        float alpha[4], p[4][4];
#pragma unroll
        for (int i = 0; i < 4; ++i) {
            float rm = -INFINITY;
#pragma unroll
            for (int j = 0; j < 4; ++j) { s[i][j] *= scale; rm = fmaxf(rm, s[i][j]); }
#pragma unroll
            for (int off = 1; off < 16; off <<= 1)
                rm = fmaxf(rm, __shfl_xor(rm, off, 16));
            float mnew = fmaxf(mrow[i], rm);
            alpha[i] = expf(mrow[i] - mnew);   // first tile: exp(-inf)=0
            float rs = 0.f;
#pragma unroll
            for (int j = 0; j < 4; ++j) { p[i][j] = expf(s[i][j] - mnew); rs += p[i][j]; }
#pragma unroll
            for (int off = 1; off < 16; off <<= 1)
                rs += __shfl_xor(rs, off, 16);
            lrow[i] = lrow[i] * alpha[i] + rs;
            mrow[i] = mnew;
        }

        __syncthreads();   // all lanes done reading KPs as K
#pragma unroll
        for (int i = 0; i < 4; ++i)
            *(float4*)&KPs[ty * 4 + i][tx * 4] =
                make_float4(p[i][0], p[i][1], p[i][2], p[i][3]);
        __syncthreads();   // P visible

#pragma unroll
        for (int i = 0; i < 4; ++i) {
            O4[i].x *= alpha[i]; O4[i].y *= alpha[i];
            O4[i].z *= alpha[i]; O4[i].w *= alpha[i];
        }

        // O += P * Vd  (full P rows from LDS, Vd columns tx*4..tx*4+3)
#pragma unroll
        for (int j4 = 0; j4 < 16; ++j4) {
            float4 vv[4];
#pragma unroll
            for (int jj = 0; jj < 4; ++jj)
                vv[jj] = *(const float4*)&Vs[j4 * 4 + jj][tx * 4];
#pragma unroll
            for (int i = 0; i < 4; ++i) {
                float4 pp = *(const float4*)&KPs[ty * 4 + i][j4 * 4];
                O4[i].x = fmaf(pp.x, vv[0].x, fmaf(pp.y, vv[1].x, fmaf(pp.z, vv[2].x, fmaf(pp.w, vv[3].x, O4[i].x))));
                O4[i].y = fmaf(pp.x, vv[0].y, fmaf(pp.y, vv[1].y, fmaf(pp.z, vv[2].y, fmaf(pp.w, vv[3].y, O4[i].y))));
                O4[i].z = fmaf(pp.x, vv[0].z, fmaf(pp.y, vv[1].z, fmaf(pp.z, vv[2].z, fmaf(pp.w, vv[3].z, O4[i].z))));
                O4[i].w = fmaf(pp.x, vv[0].w, fmaf(pp.y, vv[1].w, fmaf(pp.z, vv[2].w, fmaf(pp.w, vv[3].w, O4[i].w))));
            }
        }
        __syncthreads();   // done with KPs/Vs before next tile's load
    }

    const float lam = lam_p[0];
#pragma unroll
    for (int i = 0; i < 4; ++i) {
        const float inv = lam / lrow[i];
        int r = q0 + ty * 4 + i;
        float4 o = make_float4(O4[i].x * inv, O4[i].y * inv, O4[i].z * inv, O4[i].w * inv);
        *(float4*)&o_ws[(size_t)(b * L + r) * 1024 + h * 64 + tx * 4] = o;
    }
}

extern "C" void kernel_launch(void* const* d_in, const int* in_sizes, int n_in,
                              void* d_out, int out_size, void* d_ws, size_t ws_size,
                              hipStream_t stream) {
    const float* x     = (const float*)d_in[0];   // [2,2048,1024]
    const float* w_qkv = (const float*)d_in[1];   // [3072,1024]
    const float* b_qkv = (const float*)d_in[2];   // [3072]
    const float* w_out = (const float*)d_in[3];   // [1024,1024]
    const float* b_out = (const float*)d_in[4];   // [1024]
    const float* lam   = (const float*)d_in[5];   // [1]
    float* out = (float*)d_out;                   // [2,2048,1024] fp32

    float* qkv  = (float*)d_ws;                       // 4096*3072 f32 = 48 MB
    float* o_ws = qkv + (size_t)4096 * 3072;          // 4096*1024 f32 = 16 MB

    dim3 blk(256);
    // qkv = x @ w_qkv^T + b_qkv   : M=4096, N=3072, K=1024
    gemm_nt_bias<<<dim3(3072 / TILE, 4096 / TILE), blk, 0, stream>>>(
        x, w_qkv, b_qkv, qkv, 4096, 3072, 1024);
    // fused differential attention -> o_ws
    diff_attn<<<dim3(2048 / 64, 32), blk, 0, stream>>>(qkv, lam, o_ws);
    // out = o @ w_out^T + b_out   : M=4096, N=1024, K=1024
    gemm_nt_bias<<<dim3(1024 / TILE, 4096 / TILE), blk, 0, stream>>>(
        o_ws, w_out, b_out, out, 4096, 1024, 1024);
}

// Round 2
// 300.740 us; speedup vs baseline: 3.9201x; 3.9201x over previous
//
#include <hip/hip_runtime.h>
#include <hip/hip_bf16.h>
#include <stdint.h>

// bf16 MFMA pipeline. B=2, L=2048, D=1024, H=16, dh=64, scale = 1/32.
// a2 = softmax(s_prev) is a column permutation of a1 -> o = lam * A1 @ (v - roll(v,-1)).

typedef __attribute__((ext_vector_type(8))) short s16x8;
typedef __attribute__((ext_vector_type(4))) float f32x4;

__device__ __forceinline__ float bf2f(unsigned short u) {
    union { unsigned int i; float f; } x; x.i = ((unsigned int)u) << 16; return x.f;
}
__device__ __forceinline__ unsigned short f2bf(float f) {
    union { float f; unsigned int i; } x; x.f = f;
    unsigned int r = x.i + 0x7FFFu + ((x.i >> 16) & 1u);   // RNE
    return (unsigned short)(r >> 16);
}

// async global->LDS, 16B per lane; lds ptr must be wave-uniform (dest = base + lane*16)
__device__ __forceinline__ void gload16(const void* g, void* l) {
    auto gp = reinterpret_cast<const __attribute__((address_space(1))) unsigned int*>(
        reinterpret_cast<uintptr_t>(g));
    auto lp = reinterpret_cast<__attribute__((address_space(3))) unsigned int*>(
        reinterpret_cast<uintptr_t>(l));
    __builtin_amdgcn_global_load_lds(gp, lp, 16, 0, 0);
}

__global__ __launch_bounds__(256) void cvt_f32_bf16(
    const float* __restrict__ a, unsigned short* __restrict__ o, int n)
{
    int i = (blockIdx.x * 256 + threadIdx.x) * 4;
    if (i < n) {
        float4 v = *(const float4*)(a + i);
        ushort4 u;
        u.x = f2bf(v.x); u.y = f2bf(v.y); u.z = f2bf(v.z); u.w = f2bf(v.w);
        *(ushort4*)(o + i) = u;
    }
}

// C[m,n] = sum_k A[m,k]*Bm[n,k] + bias[n].  A:[M,K] bf16, Bm:[N,K] bf16.
// 128x128 tile, BK=32, 4 waves in 2x2 (64x64 each), 16x16x32 MFMA.
template <int OUT_BF16>
__global__ __launch_bounds__(256) void gemm_nt_mfma(
    const unsigned short* __restrict__ A,
    const unsigned short* __restrict__ Bm,
    const float* __restrict__ bias,
    void* __restrict__ C,
    int M, int N, int K)
{
    __shared__ unsigned short As[2][128][32];
    __shared__ unsigned short Bs[2][128][32];

    const int tid = threadIdx.x;
    const int wave = tid >> 6, lane = tid & 63;
    const int quad = lane >> 4, ln = lane & 15;
    const int wm = (wave >> 1) * 64, wn = (wave & 1) * 64;
    const int m0 = blockIdx.y * 128, n0 = blockIdx.x * 128;
    const int rA = wave * 16 + (lane >> 2);   // staging row within tile-half
    const int gsl = lane & 3;                  // 8-elem slot within row

    f32x4 acc[4][4];
#pragma unroll
    for (int mt = 0; mt < 4; ++mt)
#pragma unroll
        for (int nt = 0; nt < 4; ++nt) acc[mt][nt] = f32x4{0.f, 0.f, 0.f, 0.f};

    auto stage = [&](int p, int k0) {
#pragma unroll
        for (int q = 0; q < 2; ++q) {
            int row = q * 64 + rA;
            int kg = gsl ^ ((row >> 1) & 3);   // XOR swizzle: slot gsl holds kgroup kg
            gload16(A + (size_t)(m0 + row) * K + k0 + kg * 8,
                    &As[p][q * 64 + wave * 16][0]);
            gload16(Bm + (size_t)(n0 + row) * K + k0 + kg * 8,
                    &Bs[p][q * 64 + wave * 16][0]);
        }
    };

    stage(0, 0);
    __syncthreads();
    int p = 0;
    for (int k0 = 0; k0 < K; k0 += 32) {
        if (k0 + 32 < K) stage(p ^ 1, k0 + 32);
        s16x8 af[4], bfr[4];
#pragma unroll
        for (int mt = 0; mt < 4; ++mt) {
            int rr = wm + mt * 16 + ln;
            af[mt] = *(const s16x8*)&As[p][rr][((quad ^ ((rr >> 1) & 3)) & 3) * 8];
        }
#pragma unroll
        for (int nt = 0; nt < 4; ++nt) {
            int rr = wn + nt * 16 + ln;
            bfr[nt] = *(const s16x8*)&Bs[p][rr][((quad ^ ((rr >> 1) & 3)) & 3) * 8];
        }
#pragma unroll
        for (int mt = 0; mt < 4; ++mt)
#pragma unroll
            for (int nt = 0; nt < 4; ++nt)
                acc[mt][nt] = __builtin_amdgcn_mfma_f32_16x16x32_bf16(
                    af[mt], bfr[nt], acc[mt][nt], 0, 0, 0);
        __syncthreads();
        p ^= 1;
    }

    float bb[4];
#pragma unroll
    for (int nt = 0; nt < 4; ++nt) bb[nt] = bias[n0 + wn + nt * 16 + ln];
#pragma unroll
    for (int mt = 0; mt < 4; ++mt)
#pragma unroll
        for (int nt = 0; nt < 4; ++nt)
#pragma unroll
            for (int rg = 0; rg < 4; ++rg) {
                // C/D layout: col = lane&15, row = quad*4 + rg  (m89/m91-verified)
                int row = m0 + wm + mt * 16 + quad * 4 + rg;
                int col = n0 + wn + nt * 16 + ln;
                float v = acc[mt][nt][rg] + bb[nt];
                if (OUT_BF16)
                    ((unsigned short*)C)[(size_t)row * N + col] = f2bf(v);
                else
                    ((float*)C)[(size_t)row * N + col] = v;
            }
}

// Flash-style differential attention. Block = 4 waves; wave w owns q-rows q0+16w..+15.
__global__ __launch_bounds__(256) void diff_attn_mfma(
    const unsigned short* __restrict__ qkv,   // [B*L][3072] bf16
    const float* __restrict__ lam_p,
    unsigned short* __restrict__ o_ws)        // [B*L][1024] bf16
{
    constexpr int L = 2048, TD = 3072;
    constexpr float c = 0.045084222f;          // (1/32) * log2(e); softmax done base-2

    __shared__ unsigned short Ks[2][64][72];   // [seq][dh], stride 72 -> 2-way reads
    __shared__ unsigned short VdT[2][64][72];  // [dh][seq-swizzled]
    __shared__ unsigned short Ps[4][16][72];   // per-wave P strip [qrow][seq]

    const int tid = threadIdx.x;
    const int wave = tid >> 6, lane = tid & 63;
    const int quad = lane >> 4, ln = lane & 15;
    const int bh = blockIdx.y, b = bh >> 4, h = bh & 15;
    const int q0 = blockIdx.x * 64;
    const size_t seqbase = (size_t)b * L;
    const unsigned short* base = qkv + seqbase * TD + h * 64;

    // Q fragments held in registers for the whole loop (A-op: m=ln, k=quad*8+j)
    s16x8 qf[2];
    {
        const unsigned short* qrow = base + (size_t)(q0 + wave * 16 + ln) * TD;
        qf[0] = *(const s16x8*)(qrow + quad * 8);
        qf[1] = *(const s16x8*)(qrow + 32 + quad * 8);
    }

    float mrow[4], lrow[4];
    f32x4 Oa[4];
#pragma unroll
    for (int rg = 0; rg < 4; ++rg) { mrow[rg] = -INFINITY; lrow[rg] = 0.f; }
#pragma unroll
    for (int t = 0; t < 4; ++t) Oa[t] = f32x4{0.f, 0.f, 0.f, 0.f};

    const int r = tid >> 2;    // staging seq-row 0..63
    const int cg = tid & 3;    // staging 16-col group

    auto stage = [&](int p, int j0) {
        // K tile: row-major [seq][dh]
        const unsigned short* krow = base + 1024 + (size_t)(j0 + r) * TD + cg * 16;
        *(s16x8*)&Ks[p][r][cg * 16]     = *(const s16x8*)(krow);
        *(s16x8*)&Ks[p][r][cg * 16 + 8] = *(const s16x8*)(krow + 8);
        // Vd = v[j] - v[(j+1) mod L], stored transposed [dh][seq] with slot swizzle
        int j = j0 + r, jn = (j + 1) & (L - 1);
        const unsigned short* v0p = base + 2048 + (size_t)j * TD + cg * 16;
        const unsigned short* v1p = base + 2048 + (size_t)jn * TD + cg * 16;
        s16x8 v0a = *(const s16x8*)(v0p),     v0b = *(const s16x8*)(v0p + 8);
        s16x8 v1a = *(const s16x8*)(v1p),     v1b = *(const s16x8*)(v1p + 8);
        // element (dh=cd, seq=r) -> VdT[cd][ ((r>>3 + cg)&7)*8 + (r&7) ]
        int slot = (((r >> 3) + cg) & 7) * 8 + (r & 7);
#pragma unroll
        for (int u = 0; u < 8; ++u)
            VdT[p][cg * 16 + u][slot] = f2bf(bf2f((unsigned short)v0a[u]) - bf2f((unsigned short)v1a[u]));
#pragma unroll
        for (int u = 0; u < 8; ++u)
            VdT[p][cg * 16 + 8 + u][slot] = f2bf(bf2f((unsigned short)v0b[u]) - bf2f((unsigned short)v1b[u]));
    };

    stage(0, 0);
    __syncthreads();
    int p = 0;
    for (int kt = 0; kt < 32; ++kt) {
        if (kt + 1 < 32) stage(p ^ 1, (kt + 1) * 64);

        // ---- S = Q K^T (B-op: n=seq col=16t+ln, k=dh) ----
        f32x4 S[4];
#pragma unroll
        for (int t = 0; t < 4; ++t) {
            s16x8 k0f = *(const s16x8*)&Ks[p][t * 16 + ln][quad * 8];
            s16x8 k1f = *(const s16x8*)&Ks[p][t * 16 + ln][32 + quad * 8];
            f32x4 z = f32x4{0.f, 0.f, 0.f, 0.f};
            z = __builtin_amdgcn_mfma_f32_16x16x32_bf16(qf[0], k0f, z, 0, 0, 0);
            z = __builtin_amdgcn_mfma_f32_16x16x32_bf16(qf[1], k1f, z, 0, 0, 0);
            S[t] = z;
        }

        // ---- online softmax (per row rg; row stats shared across quad's 16 lanes) ----
        float alpha[4], pr[4][4];
#pragma unroll
        for (int rg = 0; rg < 4; ++rg) {
            float z0 = S[0][rg] * c, z1 = S[1][rg] * c, z2 = S[2][rg] * c, z3 = S[3][rg] * c;
            float rm = fmaxf(fmaxf(z0, z1), fmaxf(z2, z3));
            rm = fmaxf(rm, __shfl_xor(rm, 1));
            rm = fmaxf(rm, __shfl_xor(rm, 2));
            rm = fmaxf(rm, __shfl_xor(rm, 4));
            rm = fmaxf(rm, __shfl_xor(rm, 8));
            float mnew = fmaxf(mrow[rg], rm);
            alpha[rg] = exp2f(mrow[rg] - mnew);   // first tile: exp2(-inf)=0
            float p0 = exp2f(z0 - mnew), p1 = exp2f(z1 - mnew);
            float p2 = exp2f(z2 - mnew), p3 = exp2f(z3 - mnew);
            float rs = p0 + p1 + p2 + p3;
            rs += __shfl_xor(rs, 1);
            rs += __shfl_xor(rs, 2);
            rs += __shfl_xor(rs, 4);
            rs += __shfl_xor(rs, 8);
            lrow[rg] = lrow[rg] * alpha[rg] + rs;
            mrow[rg] = mnew;
            pr[0][rg] = p0; pr[1][rg] = p1; pr[2][rg] = p2; pr[3][rg] = p3;
        }

        // ---- P -> wave-private LDS strip (C-layout -> A-layout), no barrier needed ----
#pragma unroll
        for (int t = 0; t < 4; ++t)
#pragma unroll
            for (int rg = 0; rg < 4; ++rg)
                Ps[wave][quad * 4 + rg][t * 16 + ln] = f2bf(pr[t][rg]);

        s16x8 pf0 = *(const s16x8*)&Ps[wave][ln][quad * 8];
        s16x8 pf1 = *(const s16x8*)&Ps[wave][ln][32 + quad * 8];

        // ---- O = O*alpha + P @ Vd ----
#pragma unroll
        for (int t = 0; t < 4; ++t) {
#pragma unroll
            for (int rg = 0; rg < 4; ++rg) Oa[t][rg] *= alpha[rg];
            // B-op frag: n = 16t+ln (dh), k-group (4s+quad), slot-swizzled
            int sl0 = (((quad) + t) & 7) * 8;          // s=0: kgroup=quad
            int sl1 = (((4 + quad) + t) & 7) * 8;      // s=1: kgroup=4+quad
            s16x8 v0f = *(const s16x8*)&VdT[p][t * 16 + ln][sl0];
            s16x8 v1f = *(const s16x8*)&VdT[p][t * 16 + ln][sl1];
            Oa[t] = __builtin_amdgcn_mfma_f32_16x16x32_bf16(pf0, v0f, Oa[t], 0, 0, 0);
            Oa[t] = __builtin_amdgcn_mfma_f32_16x16x32_bf16(pf1, v1f, Oa[t], 0, 0, 0);
        }
        __syncthreads();
        p ^= 1;
    }

    const float lam = lam_p[0];
#pragma unroll
    for (int rg = 0; rg < 4; ++rg) {
        float inv = lam / lrow[rg];
        int row = q0 + wave * 16 + quad * 4 + rg;
#pragma unroll
        for (int t = 0; t < 4; ++t)
            o_ws[(seqbase + row) * 1024 + h * 64 + t * 16 + ln] = f2bf(Oa[t][rg] * inv);
    }
}

extern "C" void kernel_launch(void* const* d_in, const int* in_sizes, int n_in,
                              void* d_out, int out_size, void* d_ws, size_t ws_size,
                              hipStream_t stream) {
    const float* x     = (const float*)d_in[0];   // [2,2048,1024]
    const float* w_qkv = (const float*)d_in[1];   // [3072,1024]
    const float* b_qkv = (const float*)d_in[2];   // [3072]
    const float* w_out = (const float*)d_in[3];   // [1024,1024]
    const float* b_out = (const float*)d_in[4];   // [1024]
    const float* lam   = (const float*)d_in[5];   // [1]
    float* out = (float*)d_out;

    unsigned short* xb   = (unsigned short*)d_ws;              // 4096*1024
    unsigned short* wqb  = xb  + (size_t)4096 * 1024;          // 3072*1024
    unsigned short* wob  = wqb + (size_t)3072 * 1024;          // 1024*1024
    unsigned short* qkvb = wob + (size_t)1024 * 1024;          // 4096*3072
    unsigned short* ob   = qkvb + (size_t)4096 * 3072;         // 4096*1024

    cvt_f32_bf16<<<4096, 256, 0, stream>>>(x, xb, 4096 * 1024);
    cvt_f32_bf16<<<3072, 256, 0, stream>>>(w_qkv, wqb, 3072 * 1024);
    cvt_f32_bf16<<<1024, 256, 0, stream>>>(w_out, wob, 1024 * 1024);

    gemm_nt_mfma<1><<<dim3(3072 / 128, 4096 / 128), 256, 0, stream>>>(
        xb, wqb, b_qkv, qkvb, 4096, 3072, 1024);

    diff_attn_mfma<<<dim3(2048 / 64, 32), 256, 0, stream>>>(qkvb, lam, ob);

    gemm_nt_mfma<0><<<dim3(1024 / 128, 4096 / 128), 256, 0, stream>>>(
        ob, wob, b_out, out, 4096, 1024, 1024);
}

// Round 3
// 212.402 us; speedup vs baseline: 5.5505x; 1.4159x over previous
//
#include <hip/hip_runtime.h>
#include <hip/hip_bf16.h>
#include <stdint.h>

// bf16 MFMA pipeline, v3. B=2, L=2048, D=1024, H=16, dh=64.
// a2 = softmax(s_prev) is a column permutation of a1 -> o = lam * A1 @ (v - roll(v,-1)).
// Attention staging is pure global_load_lds (XOR-swizzled on the global side);
// softmax is max-free (|z| <~ 2.5, exp2 safe), row sums reduced once at the end.

typedef __attribute__((ext_vector_type(8))) short s16x8;
typedef __attribute__((ext_vector_type(4))) float f32x4;

__device__ __forceinline__ float bf2f(unsigned short u) {
    union { unsigned int i; float f; } x; x.i = ((unsigned int)u) << 16; return x.f;
}
__device__ __forceinline__ unsigned short f2bf(float f) {
    union { float f; unsigned int i; } x; x.f = f;
    unsigned int r = x.i + 0x7FFFu + ((x.i >> 16) & 1u);   // RNE
    return (unsigned short)(r >> 16);
}

// async global->LDS, 16B/lane; LDS dest = wave-uniform base + lane*16
__device__ __forceinline__ void gload16(const void* g, void* l) {
    auto gp = reinterpret_cast<const __attribute__((address_space(1))) unsigned int*>(
        reinterpret_cast<uintptr_t>(g));
    auto lp = reinterpret_cast<__attribute__((address_space(3))) unsigned int*>(
        reinterpret_cast<uintptr_t>(l));
    __builtin_amdgcn_global_load_lds(gp, lp, 16, 0, 0);
}

// One pass converting x, w_qkv, w_out to bf16 (saves two launch overheads).
__global__ __launch_bounds__(256) void cvt_all(
    const float* __restrict__ x, const float* __restrict__ wq,
    const float* __restrict__ wo,
    unsigned short* __restrict__ xb, unsigned short* __restrict__ wqb,
    unsigned short* __restrict__ wob)
{
    int i4 = blockIdx.x * 256 + threadIdx.x;   // float4 index
    const float* src; unsigned short* dst; int off;
    if (i4 < 1048576)            { src = x;  dst = xb;  off = i4; }
    else if (i4 < 1048576 + 786432) { src = wq; dst = wqb; off = i4 - 1048576; }
    else                         { src = wo; dst = wob; off = i4 - 1835008; }
    float4 v = ((const float4*)src)[off];
    ushort4 u;
    u.x = f2bf(v.x); u.y = f2bf(v.y); u.z = f2bf(v.z); u.w = f2bf(v.w);
    ((ushort4*)dst)[off] = u;
}

// vdt[b][h][dh][L] = v[b, j, h, dh] - v[b, (j+1)%L, h, dh], transposed via LDS.
__global__ __launch_bounds__(256) void vd_transpose(
    const unsigned short* __restrict__ qkvb, unsigned short* __restrict__ vdt)
{
    __shared__ unsigned short T[64][72];   // pad 72: 144B rows, 16B-aligned
    const int tid = threadIdx.x;
    const int j0 = blockIdx.x * 64;
    const int bh = blockIdx.y, b = bh >> 4, h = bh & 15;
    const unsigned short* vb = qkvb + (size_t)b * 2048 * 3072 + 2048 + h * 64;

    int r = tid >> 2, cq = tid & 3;
    int j = j0 + r, jn = (j + 1) & 2047;
    const unsigned short* p0 = vb + (size_t)j  * 3072 + cq * 16;
    const unsigned short* p1 = vb + (size_t)jn * 3072 + cq * 16;
    s16x8 a0 = *(const s16x8*)p0, a1 = *(const s16x8*)(p0 + 8);
    s16x8 b0 = *(const s16x8*)p1, b1 = *(const s16x8*)(p1 + 8);
#pragma unroll
    for (int u = 0; u < 8; ++u)
        T[cq * 16 + u][r] = f2bf(bf2f((unsigned short)a0[u]) - bf2f((unsigned short)b0[u]));
#pragma unroll
    for (int u = 0; u < 8; ++u)
        T[cq * 16 + 8 + u][r] = f2bf(bf2f((unsigned short)a1[u]) - bf2f((unsigned short)b1[u]));
    __syncthreads();

    int row = tid >> 2, sc = tid & 3;
    s16x8 o0 = *(const s16x8*)&T[row][sc * 16];
    s16x8 o1 = *(const s16x8*)&T[row][sc * 16 + 8];
    unsigned short* dst = vdt + ((size_t)bh * 64 + row) * 2048 + j0 + sc * 16;
    *(s16x8*)dst = o0;
    *(s16x8*)(dst + 8) = o1;
}

// C[m,n] = sum_k A[m,k]*Bm[n,k] + bias[n]; cols < nscale additionally *= smul.
template <int OUT_BF16>
__global__ __launch_bounds__(256) void gemm_nt_mfma(
    const unsigned short* __restrict__ A,
    const unsigned short* __restrict__ Bm,
    const float* __restrict__ bias,
    void* __restrict__ C,
    int M, int N, int K, int nscale, float smul)
{
    __shared__ unsigned short As[2][128][32];
    __shared__ unsigned short Bs[2][128][32];

    const int tid = threadIdx.x;
    const int wave = tid >> 6, lane = tid & 63;
    const int quad = lane >> 4, ln = lane & 15;
    const int wm = (wave >> 1) * 64, wn = (wave & 1) * 64;
    const int m0 = blockIdx.y * 128, n0 = blockIdx.x * 128;
    const int rA = wave * 16 + (lane >> 2);
    const int gsl = lane & 3;

    f32x4 acc[4][4];
#pragma unroll
    for (int mt = 0; mt < 4; ++mt)
#pragma unroll
        for (int nt = 0; nt < 4; ++nt) acc[mt][nt] = f32x4{0.f, 0.f, 0.f, 0.f};

    auto stage = [&](int p, int k0) {
#pragma unroll
        for (int q = 0; q < 2; ++q) {
            int row = q * 64 + rA;
            int kg = gsl ^ ((row >> 1) & 3);
            gload16(A + (size_t)(m0 + row) * K + k0 + kg * 8,
                    &As[p][q * 64 + wave * 16][0]);
            gload16(Bm + (size_t)(n0 + row) * K + k0 + kg * 8,
                    &Bs[p][q * 64 + wave * 16][0]);
        }
    };

    stage(0, 0);
    __syncthreads();
    int p = 0;
    for (int k0 = 0; k0 < K; k0 += 32) {
        if (k0 + 32 < K) stage(p ^ 1, k0 + 32);
        s16x8 af[4], bfr[4];
#pragma unroll
        for (int mt = 0; mt < 4; ++mt) {
            int rr = wm + mt * 16 + ln;
            af[mt] = *(const s16x8*)&As[p][rr][((quad ^ ((rr >> 1) & 3)) & 3) * 8];
        }
#pragma unroll
        for (int nt = 0; nt < 4; ++nt) {
            int rr = wn + nt * 16 + ln;
            bfr[nt] = *(const s16x8*)&Bs[p][rr][((quad ^ ((rr >> 1) & 3)) & 3) * 8];
        }
#pragma unroll
        for (int mt = 0; mt < 4; ++mt)
#pragma unroll
            for (int nt = 0; nt < 4; ++nt)
                acc[mt][nt] = __builtin_amdgcn_mfma_f32_16x16x32_bf16(
                    af[mt], bfr[nt], acc[mt][nt], 0, 0, 0);
        __syncthreads();
        p ^= 1;
    }

    float bb[4];
#pragma unroll
    for (int nt = 0; nt < 4; ++nt) bb[nt] = bias[n0 + wn + nt * 16 + ln];
#pragma unroll
    for (int mt = 0; mt < 4; ++mt)
#pragma unroll
        for (int nt = 0; nt < 4; ++nt) {
            int col = n0 + wn + nt * 16 + ln;
            float sc = (col < nscale) ? smul : 1.f;
#pragma unroll
            for (int rg = 0; rg < 4; ++rg) {
                int row = m0 + wm + mt * 16 + quad * 4 + rg;
                float v = (acc[mt][nt][rg] + bb[nt]) * sc;
                if (OUT_BF16)
                    ((unsigned short*)C)[(size_t)row * N + col] = f2bf(v);
                else
                    ((float*)C)[(size_t)row * N + col] = v;
            }
        }
}

// Flash-style differential attention, v3. Q pre-scaled by log2(e)/32 in GEMM epilogue.
__global__ __launch_bounds__(256) void diff_attn_v3(
    const unsigned short* __restrict__ qkv,   // [B*L][3072] bf16 (Q cols pre-scaled)
    const unsigned short* __restrict__ vdt,   // [B*H][64][2048] bf16
    const float* __restrict__ lam_p,
    unsigned short* __restrict__ o_ws)        // [B*L][1024] bf16
{
    constexpr int L = 2048, TD = 3072;

    __shared__ unsigned short Ks[2][64][64];  // [seq][dh], chunk-swizzled
    __shared__ unsigned short Vs[2][64][64];  // [dh][seq], chunk-swizzled
    __shared__ unsigned short Ps[4][16][64];  // per-wave P strip, chunk-swizzled

    const int tid = threadIdx.x;
    const int wave = tid >> 6, lane = tid & 63;
    const int quad = lane >> 4, ln = lane & 15;
    const int bh = blockIdx.y, b = bh >> 4, h = bh & 15;
    const int q0 = blockIdx.x * 64;
    const size_t seqbase = (size_t)b * L;
    const unsigned short* base = qkv + seqbase * TD + h * 64;
    const unsigned short* kb = base + 1024;
    const unsigned short* vbase = vdt + (size_t)bh * 64 * 2048;

    // staging lane mapping: lane covers LDS slot lane*16B; row_off = lane>>3,
    // lds chunk = lane&7, global chunk = (lane&7) ^ row_off  (rows stay ≡ row_off mod 8)
    const int lsl = lane >> 3;
    const int cgl = (lane & 7) ^ lsl;

    // Q fragments in registers for the whole loop (A-op: m=ln, k=quad*8+j)
    s16x8 qf0, qf1;
    {
        const unsigned short* qrow = base + (size_t)(q0 + wave * 16 + ln) * TD;
        qf0 = *(const s16x8*)(qrow + quad * 8);
        qf1 = *(const s16x8*)(qrow + 32 + quad * 8);
    }

    auto stage = [&](int p, int j0) {
        const unsigned short* k0p = kb + (size_t)(j0 + wave * 16 + lsl) * TD + cgl * 8;
        gload16(k0p,                 &Ks[p][wave * 16][0]);
        gload16(k0p + (size_t)8 * TD, &Ks[p][wave * 16 + 8][0]);
        const unsigned short* v0p = vbase + (size_t)(wave * 16 + lsl) * 2048 + j0 + cgl * 8;
        gload16(v0p,            &Vs[p][wave * 16][0]);
        gload16(v0p + 8 * 2048, &Vs[p][wave * 16 + 8][0]);
    };

    f32x4 Oa[4];
    float lsum[4] = {0.f, 0.f, 0.f, 0.f};
#pragma unroll
    for (int t = 0; t < 4; ++t) Oa[t] = f32x4{0.f, 0.f, 0.f, 0.f};

    const int kx0 = (quad ^ (ln & 7)) << 3;        // chunk for k-group quad
    const int kx1 = ((quad + 4) ^ (ln & 7)) << 3;  // chunk for k-group quad+4

    stage(0, 0);
    __syncthreads();
    int p = 0;
    for (int kt = 0; kt < 32; ++kt) {
        if (kt + 1 < 32) stage(p ^ 1, (kt + 1) * 64);

        // ---- S = Qs K^T  (z = s * log2e/32 directly; Q pre-scaled) ----
        f32x4 S[4];
#pragma unroll
        for (int t = 0; t < 4; ++t) {
            s16x8 k0 = *(const s16x8*)&Ks[p][t * 16 + ln][kx0];
            s16x8 k1 = *(const s16x8*)&Ks[p][t * 16 + ln][kx1];
            f32x4 z = f32x4{0.f, 0.f, 0.f, 0.f};
            z = __builtin_amdgcn_mfma_f32_16x16x32_bf16(qf0, k0, z, 0, 0, 0);
            z = __builtin_amdgcn_mfma_f32_16x16x32_bf16(qf1, k1, z, 0, 0, 0);
            S[t] = z;
        }

        // ---- max-free softmax: P = exp2(z), truncated to bf16; lsum uses the
        //      SAME truncated values so the rounding bias cancels in the ratio ----
#pragma unroll
        for (int t = 0; t < 4; ++t) {
            int colc = 2 * t + (ln >> 3);
            int wi = ln & 7;
#pragma unroll
            for (int rg = 0; rg < 4; ++rg) {
                float pv = exp2f(S[t][rg]);
                unsigned int bits = __builtin_bit_cast(unsigned int, pv);
                unsigned int tr = bits & 0xFFFF0000u;
                lsum[rg] += __builtin_bit_cast(float, tr);
                int row = quad * 4 + rg;
                Ps[wave][row][((colc ^ (row & 7)) << 3) + wi] =
                    (unsigned short)(bits >> 16);
            }
        }

        s16x8 pf0 = *(const s16x8*)&Ps[wave][ln][kx0];
        s16x8 pf1 = *(const s16x8*)&Ps[wave][ln][kx1];

        // ---- O += P @ Vd ----
#pragma unroll
        for (int t = 0; t < 4; ++t) {
            s16x8 v0 = *(const s16x8*)&Vs[p][t * 16 + ln][kx0];
            s16x8 v1 = *(const s16x8*)&Vs[p][t * 16 + ln][kx1];
            Oa[t] = __builtin_amdgcn_mfma_f32_16x16x32_bf16(pf0, v0, Oa[t], 0, 0, 0);
            Oa[t] = __builtin_amdgcn_mfma_f32_16x16x32_bf16(pf1, v1, Oa[t], 0, 0, 0);
        }
        __syncthreads();
        p ^= 1;
    }

    const float lam = lam_p[0];
#pragma unroll
    for (int rg = 0; rg < 4; ++rg) {
        float l = lsum[rg];
        l += __shfl_xor(l, 1);
        l += __shfl_xor(l, 2);
        l += __shfl_xor(l, 4);
        l += __shfl_xor(l, 8);
        float inv = lam / l;
        int row = q0 + wave * 16 + quad * 4 + rg;
#pragma unroll
        for (int t = 0; t < 4; ++t)
            o_ws[(seqbase + row) * 1024 + h * 64 + t * 16 + ln] = f2bf(Oa[t][rg] * inv);
    }
}

extern "C" void kernel_launch(void* const* d_in, const int* in_sizes, int n_in,
                              void* d_out, int out_size, void* d_ws, size_t ws_size,
                              hipStream_t stream) {
    const float* x     = (const float*)d_in[0];
    const float* w_qkv = (const float*)d_in[1];
    const float* b_qkv = (const float*)d_in[2];
    const float* w_out = (const float*)d_in[3];
    const float* b_out = (const float*)d_in[4];
    const float* lam   = (const float*)d_in[5];
    float* out = (float*)d_out;

    unsigned short* xb   = (unsigned short*)d_ws;              // 4096*1024
    unsigned short* wqb  = xb   + (size_t)4096 * 1024;         // 3072*1024
    unsigned short* wob  = wqb  + (size_t)3072 * 1024;         // 1024*1024
    unsigned short* qkvb = wob  + (size_t)1024 * 1024;         // 4096*3072
    unsigned short* ob   = qkvb + (size_t)4096 * 3072;         // 4096*1024
    unsigned short* vdt  = ob   + (size_t)4096 * 1024;         // 32*64*2048

    cvt_all<<<8192, 256, 0, stream>>>(x, w_qkv, w_out, xb, wqb, wob);

    // qkv = x @ w_qkv^T + b_qkv; Q cols (n<1024) pre-scaled by log2(e)/32
    gemm_nt_mfma<1><<<dim3(24, 32), 256, 0, stream>>>(
        xb, wqb, b_qkv, qkvb, 4096, 3072, 1024, 1024, 0.045084222f);

    vd_transpose<<<dim3(32, 32), 256, 0, stream>>>(qkvb, vdt);

    diff_attn_v3<<<dim3(32, 32), 256, 0, stream>>>(qkvb, vdt, lam, ob);

    gemm_nt_mfma<0><<<dim3(8, 32), 256, 0, stream>>>(
        ob, wob, b_out, out, 4096, 1024, 1024, 0, 1.f);
}

// Round 4
// 202.894 us; speedup vs baseline: 5.8105x; 1.0469x over previous
//
#include <hip/hip_runtime.h>
#include <hip/hip_bf16.h>
#include <stdint.h>

// bf16 MFMA pipeline, v4. B=2, L=2048, D=1024, H=16, dh=64.
// a2 = softmax(s_prev) is a column permutation of a1 -> o = lam * A1 @ (v - roll(v,-1)).
// v4: attention waves own 32 q-rows (2 subtiles) so each K/V LDS fragment read
// feeds 2 MFMAs; gemm2 uses 128x64 tiles for 2 blocks/CU.

typedef __attribute__((ext_vector_type(8))) short s16x8;
typedef __attribute__((ext_vector_type(4))) float f32x4;

__device__ __forceinline__ float bf2f(unsigned short u) {
    union { unsigned int i; float f; } x; x.i = ((unsigned int)u) << 16; return x.f;
}
__device__ __forceinline__ unsigned short f2bf(float f) {
    union { float f; unsigned int i; } x; x.f = f;
    unsigned int r = x.i + 0x7FFFu + ((x.i >> 16) & 1u);   // RNE
    return (unsigned short)(r >> 16);
}

// async global->LDS, 16B/lane; LDS dest = wave-uniform base + lane*16
__device__ __forceinline__ void gload16(const void* g, void* l) {
    auto gp = reinterpret_cast<const __attribute__((address_space(1))) unsigned int*>(
        reinterpret_cast<uintptr_t>(g));
    auto lp = reinterpret_cast<__attribute__((address_space(3))) unsigned int*>(
        reinterpret_cast<uintptr_t>(l));
    __builtin_amdgcn_global_load_lds(gp, lp, 16, 0, 0);
}

__global__ __launch_bounds__(256) void cvt_all(
    const float* __restrict__ x, const float* __restrict__ wq,
    const float* __restrict__ wo,
    unsigned short* __restrict__ xb, unsigned short* __restrict__ wqb,
    unsigned short* __restrict__ wob)
{
    int i4 = blockIdx.x * 256 + threadIdx.x;   // float4 index
    const float* src; unsigned short* dst; int off;
    if (i4 < 1048576)            { src = x;  dst = xb;  off = i4; }
    else if (i4 < 1048576 + 786432) { src = wq; dst = wqb; off = i4 - 1048576; }
    else                         { src = wo; dst = wob; off = i4 - 1835008; }
    float4 v = ((const float4*)src)[off];
    ushort4 u;
    u.x = f2bf(v.x); u.y = f2bf(v.y); u.z = f2bf(v.z); u.w = f2bf(v.w);
    ((ushort4*)dst)[off] = u;
}

// vdt[b][h][dh][L] = v[b, j, h, dh] - v[b, (j+1)%L, h, dh], transposed via LDS.
__global__ __launch_bounds__(256) void vd_transpose(
    const unsigned short* __restrict__ qkvb, unsigned short* __restrict__ vdt)
{
    __shared__ unsigned short T[64][72];
    const int tid = threadIdx.x;
    const int j0 = blockIdx.x * 64;
    const int bh = blockIdx.y, b = bh >> 4, h = bh & 15;
    const unsigned short* vb = qkvb + (size_t)b * 2048 * 3072 + 2048 + h * 64;

    int r = tid >> 2, cq = tid & 3;
    int j = j0 + r, jn = (j + 1) & 2047;
    const unsigned short* p0 = vb + (size_t)j  * 3072 + cq * 16;
    const unsigned short* p1 = vb + (size_t)jn * 3072 + cq * 16;
    s16x8 a0 = *(const s16x8*)p0, a1 = *(const s16x8*)(p0 + 8);
    s16x8 b0 = *(const s16x8*)p1, b1 = *(const s16x8*)(p1 + 8);
#pragma unroll
    for (int u = 0; u < 8; ++u)
        T[cq * 16 + u][r] = f2bf(bf2f((unsigned short)a0[u]) - bf2f((unsigned short)b0[u]));
#pragma unroll
    for (int u = 0; u < 8; ++u)
        T[cq * 16 + 8 + u][r] = f2bf(bf2f((unsigned short)a1[u]) - bf2f((unsigned short)b1[u]));
    __syncthreads();

    int row = tid >> 2, sc = tid & 3;
    s16x8 o0 = *(const s16x8*)&T[row][sc * 16];
    s16x8 o1 = *(const s16x8*)&T[row][sc * 16 + 8];
    unsigned short* dst = vdt + ((size_t)bh * 64 + row) * 2048 + j0 + sc * 16;
    *(s16x8*)dst = o0;
    *(s16x8*)(dst + 8) = o1;
}

// C[m,n] = sum_k A[m,k]*Bm[n,k] + bias[n]; cols < nscale additionally *= smul.
// Block tile 128 x BN; BN=128: 4 waves 2x2 of 64x64; BN=64: 4 waves 2x2 of 64x32.
template <int OUT_BF16, int BN>
__global__ __launch_bounds__(256) void gemm_nt_mfma(
    const unsigned short* __restrict__ A,
    const unsigned short* __restrict__ Bm,
    const float* __restrict__ bias,
    void* __restrict__ C,
    int M, int N, int K, int nscale, float smul)
{
    constexpr int NT = BN / 32;
    __shared__ unsigned short As[2][128][32];
    __shared__ unsigned short Bs[2][BN][32];

    const int tid = threadIdx.x;
    const int wave = tid >> 6, lane = tid & 63;
    const int quad = lane >> 4, ln = lane & 15;
    const int wm = (wave >> 1) * 64, wn = (wave & 1) * (NT * 16);
    const int m0 = blockIdx.y * 128, n0 = blockIdx.x * BN;
    const int rA = wave * 16 + (lane >> 2);
    const int gsl = lane & 3;

    f32x4 acc[4][NT];
#pragma unroll
    for (int mt = 0; mt < 4; ++mt)
#pragma unroll
        for (int nt = 0; nt < NT; ++nt) acc[mt][nt] = f32x4{0.f, 0.f, 0.f, 0.f};

    auto stage = [&](int p, int k0) {
#pragma unroll
        for (int q = 0; q < 2; ++q) {
            int row = q * 64 + rA;
            int kg = gsl ^ ((row >> 1) & 3);
            gload16(A + (size_t)(m0 + row) * K + k0 + kg * 8,
                    &As[p][q * 64 + wave * 16][0]);
            if (q * 64 < BN)
                gload16(Bm + (size_t)(n0 + row) * K + k0 + kg * 8,
                        &Bs[p][q * 64 + wave * 16][0]);
        }
    };

    stage(0, 0);
    __syncthreads();
    int p = 0;
    for (int k0 = 0; k0 < K; k0 += 32) {
        if (k0 + 32 < K) stage(p ^ 1, k0 + 32);
        s16x8 af[4], bfr[NT];
#pragma unroll
        for (int mt = 0; mt < 4; ++mt) {
            int rr = wm + mt * 16 + ln;
            af[mt] = *(const s16x8*)&As[p][rr][((quad ^ ((rr >> 1) & 3)) & 3) * 8];
        }
#pragma unroll
        for (int nt = 0; nt < NT; ++nt) {
            int rr = wn + nt * 16 + ln;
            bfr[nt] = *(const s16x8*)&Bs[p][rr][((quad ^ ((rr >> 1) & 3)) & 3) * 8];
        }
#pragma unroll
        for (int mt = 0; mt < 4; ++mt)
#pragma unroll
            for (int nt = 0; nt < NT; ++nt)
                acc[mt][nt] = __builtin_amdgcn_mfma_f32_16x16x32_bf16(
                    af[mt], bfr[nt], acc[mt][nt], 0, 0, 0);
        __syncthreads();
        p ^= 1;
    }

    float bb[NT];
#pragma unroll
    for (int nt = 0; nt < NT; ++nt) bb[nt] = bias[n0 + wn + nt * 16 + ln];
#pragma unroll
    for (int mt = 0; mt < 4; ++mt)
#pragma unroll
        for (int nt = 0; nt < NT; ++nt) {
            int col = n0 + wn + nt * 16 + ln;
            float sc = (col < nscale) ? smul : 1.f;
#pragma unroll
            for (int rg = 0; rg < 4; ++rg) {
                int row = m0 + wm + mt * 16 + quad * 4 + rg;
                float v = (acc[mt][nt][rg] + bb[nt]) * sc;
                if (OUT_BF16)
                    ((unsigned short*)C)[(size_t)row * N + col] = f2bf(v);
                else
                    ((float*)C)[(size_t)row * N + col] = v;
            }
        }
}

// Flash-style differential attention, v4: wave owns 32 q-rows (2 x 16-row subtiles).
// Block = 4 waves = 128 q-rows; grid (16, 32).
__global__ __launch_bounds__(256) void diff_attn_v4(
    const unsigned short* __restrict__ qkv,   // [B*L][3072] bf16 (Q pre-scaled)
    const unsigned short* __restrict__ vdt,   // [B*H][64][2048] bf16
    const float* __restrict__ lam_p,
    unsigned short* __restrict__ o_ws)        // [B*L][1024] bf16
{
    constexpr int L = 2048, TD = 3072;

    __shared__ unsigned short Ks[2][64][64];  // [seq][dh], chunk-swizzled
    __shared__ unsigned short Vs[2][64][64];  // [dh][seq], chunk-swizzled
    __shared__ unsigned short Ps[4][32][64];  // per-wave P strip, chunk-swizzled

    const int tid = threadIdx.x;
    const int wave = tid >> 6, lane = tid & 63;
    const int quad = lane >> 4, ln = lane & 15;
    const int bh = blockIdx.y, b = bh >> 4, h = bh & 15;
    const int q0 = blockIdx.x * 128;
    const size_t seqbase = (size_t)b * L;
    const unsigned short* base = qkv + seqbase * TD + h * 64;
    const unsigned short* kb = base + 1024;
    const unsigned short* vbase = vdt + (size_t)bh * 64 * 2048;

    const int lsl = lane >> 3;
    const int cgl = (lane & 7) ^ lsl;

    // Q fragments for both 16-row subtiles (A-op: m=ln, k=quad*8+u)
    s16x8 qf[2][2];
#pragma unroll
    for (int s = 0; s < 2; ++s) {
        const unsigned short* qrow =
            base + (size_t)(q0 + wave * 32 + s * 16 + ln) * TD;
        qf[s][0] = *(const s16x8*)(qrow + quad * 8);
        qf[s][1] = *(const s16x8*)(qrow + 32 + quad * 8);
    }

    auto stage = [&](int p, int j0) {
        const unsigned short* k0p = kb + (size_t)(j0 + wave * 16 + lsl) * TD + cgl * 8;
        gload16(k0p,                  &Ks[p][wave * 16][0]);
        gload16(k0p + (size_t)8 * TD, &Ks[p][wave * 16 + 8][0]);
        const unsigned short* v0p = vbase + (size_t)(wave * 16 + lsl) * 2048 + j0 + cgl * 8;
        gload16(v0p,            &Vs[p][wave * 16][0]);
        gload16(v0p + 8 * 2048, &Vs[p][wave * 16 + 8][0]);
    };

    f32x4 Oa[2][4];
    float lsum[2][4];
#pragma unroll
    for (int s = 0; s < 2; ++s)
#pragma unroll
        for (int t = 0; t < 4; ++t) Oa[s][t] = f32x4{0.f, 0.f, 0.f, 0.f};
#pragma unroll
    for (int s = 0; s < 2; ++s)
#pragma unroll
        for (int rg = 0; rg < 4; ++rg) lsum[s][rg] = 0.f;

    const int kx0 = (quad ^ (ln & 7)) << 3;
    const int kx1 = ((quad + 4) ^ (ln & 7)) << 3;

    stage(0, 0);
    __syncthreads();
    int p = 0;
    for (int kt = 0; kt < 32; ++kt) {
        if (kt + 1 < 32) stage(p ^ 1, (kt + 1) * 64);

        // ---- S = Qs K^T; K frags reused across both q-subtiles ----
        f32x4 S[2][4];
#pragma unroll
        for (int t = 0; t < 4; ++t) {
            s16x8 k0 = *(const s16x8*)&Ks[p][t * 16 + ln][kx0];
            s16x8 k1 = *(const s16x8*)&Ks[p][t * 16 + ln][kx1];
#pragma unroll
            for (int s = 0; s < 2; ++s) {
                f32x4 z = f32x4{0.f, 0.f, 0.f, 0.f};
                z = __builtin_amdgcn_mfma_f32_16x16x32_bf16(qf[s][0], k0, z, 0, 0, 0);
                z = __builtin_amdgcn_mfma_f32_16x16x32_bf16(qf[s][1], k1, z, 0, 0, 0);
                S[s][t] = z;
            }
        }

        // ---- max-free softmax; lsum sums the same truncated values the MFMA eats ----
#pragma unroll
        for (int s = 0; s < 2; ++s)
#pragma unroll
            for (int t = 0; t < 4; ++t) {
                int colc = 2 * t + (ln >> 3);
                int wi = ln & 7;
#pragma unroll
                for (int rg = 0; rg < 4; ++rg) {
                    float pv = __builtin_amdgcn_exp2f(S[s][t][rg]);
                    unsigned int bits = __builtin_bit_cast(unsigned int, pv);
                    unsigned int tr = bits & 0xFFFF0000u;
                    lsum[s][rg] += __builtin_bit_cast(float, tr);
                    int row = quad * 4 + rg;
                    Ps[wave][s * 16 + row][((colc ^ (row & 7)) << 3) + wi] =
                        (unsigned short)(bits >> 16);
                }
            }

        s16x8 pf[2][2];
#pragma unroll
        for (int s = 0; s < 2; ++s) {
            pf[s][0] = *(const s16x8*)&Ps[wave][s * 16 + ln][kx0];
            pf[s][1] = *(const s16x8*)&Ps[wave][s * 16 + ln][kx1];
        }

        // ---- O += P @ Vd; V frags reused across both q-subtiles ----
#pragma unroll
        for (int t = 0; t < 4; ++t) {
            s16x8 v0 = *(const s16x8*)&Vs[p][t * 16 + ln][kx0];
            s16x8 v1 = *(const s16x8*)&Vs[p][t * 16 + ln][kx1];
#pragma unroll
            for (int s = 0; s < 2; ++s) {
                Oa[s][t] = __builtin_amdgcn_mfma_f32_16x16x32_bf16(pf[s][0], v0, Oa[s][t], 0, 0, 0);
                Oa[s][t] = __builtin_amdgcn_mfma_f32_16x16x32_bf16(pf[s][1], v1, Oa[s][t], 0, 0, 0);
            }
        }
        __syncthreads();
        p ^= 1;
    }

    const float lam = lam_p[0];
#pragma unroll
    for (int s = 0; s < 2; ++s)
#pragma unroll
        for (int rg = 0; rg < 4; ++rg) {
            float l = lsum[s][rg];
            l += __shfl_xor(l, 1);
            l += __shfl_xor(l, 2);
            l += __shfl_xor(l, 4);
            l += __shfl_xor(l, 8);
            float inv = lam / l;
            int row = q0 + wave * 32 + s * 16 + quad * 4 + rg;
#pragma unroll
            for (int t = 0; t < 4; ++t)
                o_ws[(seqbase + row) * 1024 + h * 64 + t * 16 + ln] =
                    f2bf(Oa[s][t][rg] * inv);
        }
}

extern "C" void kernel_launch(void* const* d_in, const int* in_sizes, int n_in,
                              void* d_out, int out_size, void* d_ws, size_t ws_size,
                              hipStream_t stream) {
    const float* x     = (const float*)d_in[0];
    const float* w_qkv = (const float*)d_in[1];
    const float* b_qkv = (const float*)d_in[2];
    const float* w_out = (const float*)d_in[3];
    const float* b_out = (const float*)d_in[4];
    const float* lam   = (const float*)d_in[5];
    float* out = (float*)d_out;

    unsigned short* xb   = (unsigned short*)d_ws;
    unsigned short* wqb  = xb   + (size_t)4096 * 1024;
    unsigned short* wob  = wqb  + (size_t)3072 * 1024;
    unsigned short* qkvb = wob  + (size_t)1024 * 1024;
    unsigned short* ob   = qkvb + (size_t)4096 * 3072;
    unsigned short* vdt  = ob   + (size_t)4096 * 1024;

    cvt_all<<<8192, 256, 0, stream>>>(x, w_qkv, w_out, xb, wqb, wob);

    // qkv = x @ w_qkv^T + b_qkv; Q cols (n<1024) pre-scaled by log2(e)/32
    gemm_nt_mfma<1, 128><<<dim3(24, 32), 256, 0, stream>>>(
        xb, wqb, b_qkv, qkvb, 4096, 3072, 1024, 1024, 0.045084222f);

    vd_transpose<<<dim3(32, 32), 256, 0, stream>>>(qkvb, vdt);

    diff_attn_v4<<<dim3(16, 32), 256, 0, stream>>>(qkvb, vdt, lam, ob);

    gemm_nt_mfma<0, 64><<<dim3(16, 32), 256, 0, stream>>>(
        ob, wob, b_out, out, 4096, 1024, 1024, 0, 1.f);
}

// Round 5
// 198.375 us; speedup vs baseline: 5.9429x; 1.0228x over previous
//
#include <hip/hip_runtime.h>
#include <hip/hip_bf16.h>
#include <stdint.h>

// bf16 MFMA pipeline, v5. B=2, L=2048, D=1024, H=16, dh=64.
// a2 = softmax(s_prev) is a column permutation of a1 -> o = lam * A1 @ (v - roll(v,-1)).
// v5: compute S^T = K·Q^T so P^T stays in registers (C-layout of S^T == B-operand
// layout of 16x16x16 PV MFMA). No P LDS round-trip; row-sums via ones-MFMA.

typedef __attribute__((ext_vector_type(8))) short s16x8;
typedef __attribute__((ext_vector_type(4))) short s16x4;
typedef __attribute__((ext_vector_type(4))) float f32x4;

__device__ __forceinline__ float bf2f(unsigned short u) {
    union { unsigned int i; float f; } x; x.i = ((unsigned int)u) << 16; return x.f;
}
__device__ __forceinline__ unsigned short f2bf(float f) {
    union { float f; unsigned int i; } x; x.f = f;
    unsigned int r = x.i + 0x7FFFu + ((x.i >> 16) & 1u);   // RNE
    return (unsigned short)(r >> 16);
}

__device__ __forceinline__ f32x4 mfma16(s16x4 a, s16x4 b, f32x4 c) {
#if __has_builtin(__builtin_amdgcn_mfma_f32_16x16x16bf16_1k)
    return __builtin_amdgcn_mfma_f32_16x16x16bf16_1k(a, b, c, 0, 0, 0);
#else
    f32x4 d;
    asm volatile("v_mfma_f32_16x16x16_bf16 %0, %1, %2, %3\n\ts_nop 7\n\ts_nop 3"
                 : "=v"(d) : "v"(a), "v"(b), "v"(c));
    return d;
#endif
}

// async global->LDS, 16B/lane; LDS dest = wave-uniform base + lane*16
__device__ __forceinline__ void gload16(const void* g, void* l) {
    auto gp = reinterpret_cast<const __attribute__((address_space(1))) unsigned int*>(
        reinterpret_cast<uintptr_t>(g));
    auto lp = reinterpret_cast<__attribute__((address_space(3))) unsigned int*>(
        reinterpret_cast<uintptr_t>(l));
    __builtin_amdgcn_global_load_lds(gp, lp, 16, 0, 0);
}

__global__ __launch_bounds__(256) void cvt_all(
    const float* __restrict__ x, const float* __restrict__ wq,
    const float* __restrict__ wo,
    unsigned short* __restrict__ xb, unsigned short* __restrict__ wqb,
    unsigned short* __restrict__ wob)
{
    int i4 = blockIdx.x * 256 + threadIdx.x;   // float4 index
    const float* src; unsigned short* dst; int off;
    if (i4 < 1048576)            { src = x;  dst = xb;  off = i4; }
    else if (i4 < 1048576 + 786432) { src = wq; dst = wqb; off = i4 - 1048576; }
    else                         { src = wo; dst = wob; off = i4 - 1835008; }
    float4 v = ((const float4*)src)[off];
    ushort4 u;
    u.x = f2bf(v.x); u.y = f2bf(v.y); u.z = f2bf(v.z); u.w = f2bf(v.w);
    ((ushort4*)dst)[off] = u;
}

// vdt[b][h][dh][L] = v[b, j, h, dh] - v[b, (j+1)%L, h, dh], transposed via LDS.
__global__ __launch_bounds__(256) void vd_transpose(
    const unsigned short* __restrict__ qkvb, unsigned short* __restrict__ vdt)
{
    __shared__ unsigned short T[64][72];
    const int tid = threadIdx.x;
    const int j0 = blockIdx.x * 64;
    const int bh = blockIdx.y, b = bh >> 4, h = bh & 15;
    const unsigned short* vb = qkvb + (size_t)b * 2048 * 3072 + 2048 + h * 64;

    int r = tid >> 2, cq = tid & 3;
    int j = j0 + r, jn = (j + 1) & 2047;
    const unsigned short* p0 = vb + (size_t)j  * 3072 + cq * 16;
    const unsigned short* p1 = vb + (size_t)jn * 3072 + cq * 16;
    s16x8 a0 = *(const s16x8*)p0, a1 = *(const s16x8*)(p0 + 8);
    s16x8 b0 = *(const s16x8*)p1, b1 = *(const s16x8*)(p1 + 8);
#pragma unroll
    for (int u = 0; u < 8; ++u)
        T[cq * 16 + u][r] = f2bf(bf2f((unsigned short)a0[u]) - bf2f((unsigned short)b0[u]));
#pragma unroll
    for (int u = 0; u < 8; ++u)
        T[cq * 16 + 8 + u][r] = f2bf(bf2f((unsigned short)a1[u]) - bf2f((unsigned short)b1[u]));
    __syncthreads();

    int row = tid >> 2, sc = tid & 3;
    s16x8 o0 = *(const s16x8*)&T[row][sc * 16];
    s16x8 o1 = *(const s16x8*)&T[row][sc * 16 + 8];
    unsigned short* dst = vdt + ((size_t)bh * 64 + row) * 2048 + j0 + sc * 16;
    *(s16x8*)dst = o0;
    *(s16x8*)(dst + 8) = o1;
}

// C[m,n] = sum_k A[m,k]*Bm[n,k] + bias[n]; cols < nscale additionally *= smul.
template <int OUT_BF16, int BN>
__global__ __launch_bounds__(256) void gemm_nt_mfma(
    const unsigned short* __restrict__ A,
    const unsigned short* __restrict__ Bm,
    const float* __restrict__ bias,
    void* __restrict__ C,
    int M, int N, int K, int nscale, float smul)
{
    constexpr int NT = BN / 32;
    __shared__ unsigned short As[2][128][32];
    __shared__ unsigned short Bs[2][BN][32];

    const int tid = threadIdx.x;
    const int wave = tid >> 6, lane = tid & 63;
    const int quad = lane >> 4, ln = lane & 15;
    const int wm = (wave >> 1) * 64, wn = (wave & 1) * (NT * 16);
    const int m0 = blockIdx.y * 128, n0 = blockIdx.x * BN;
    const int rA = wave * 16 + (lane >> 2);
    const int gsl = lane & 3;

    f32x4 acc[4][NT];
#pragma unroll
    for (int mt = 0; mt < 4; ++mt)
#pragma unroll
        for (int nt = 0; nt < NT; ++nt) acc[mt][nt] = f32x4{0.f, 0.f, 0.f, 0.f};

    auto stage = [&](int p, int k0) {
#pragma unroll
        for (int q = 0; q < 2; ++q) {
            int row = q * 64 + rA;
            int kg = gsl ^ ((row >> 1) & 3);
            gload16(A + (size_t)(m0 + row) * K + k0 + kg * 8,
                    &As[p][q * 64 + wave * 16][0]);
            if (q * 64 < BN)
                gload16(Bm + (size_t)(n0 + row) * K + k0 + kg * 8,
                        &Bs[p][q * 64 + wave * 16][0]);
        }
    };

    stage(0, 0);
    __syncthreads();
    int p = 0;
    for (int k0 = 0; k0 < K; k0 += 32) {
        if (k0 + 32 < K) stage(p ^ 1, k0 + 32);
        s16x8 af[4], bfr[NT];
#pragma unroll
        for (int mt = 0; mt < 4; ++mt) {
            int rr = wm + mt * 16 + ln;
            af[mt] = *(const s16x8*)&As[p][rr][((quad ^ ((rr >> 1) & 3)) & 3) * 8];
        }
#pragma unroll
        for (int nt = 0; nt < NT; ++nt) {
            int rr = wn + nt * 16 + ln;
            bfr[nt] = *(const s16x8*)&Bs[p][rr][((quad ^ ((rr >> 1) & 3)) & 3) * 8];
        }
#pragma unroll
        for (int mt = 0; mt < 4; ++mt)
#pragma unroll
            for (int nt = 0; nt < NT; ++nt)
                acc[mt][nt] = __builtin_amdgcn_mfma_f32_16x16x32_bf16(
                    af[mt], bfr[nt], acc[mt][nt], 0, 0, 0);
        __syncthreads();
        p ^= 1;
    }

    float bb[NT];
#pragma unroll
    for (int nt = 0; nt < NT; ++nt) bb[nt] = bias[n0 + wn + nt * 16 + ln];
#pragma unroll
    for (int mt = 0; mt < 4; ++mt)
#pragma unroll
        for (int nt = 0; nt < NT; ++nt) {
            int col = n0 + wn + nt * 16 + ln;
            float sc = (col < nscale) ? smul : 1.f;
#pragma unroll
            for (int rg = 0; rg < 4; ++rg) {
                int row = m0 + wm + mt * 16 + quad * 4 + rg;
                float v = (acc[mt][nt][rg] + bb[nt]) * sc;
                if (OUT_BF16)
                    ((unsigned short*)C)[(size_t)row * N + col] = f2bf(v);
                else
                    ((float*)C)[(size_t)row * N + col] = v;
            }
        }
}

// Differential attention, v5: S^T/P^T-in-register flash. Wave owns 32 q-rows.
// Block = 4 waves = 128 q-rows; grid (16, 32).
__global__ __launch_bounds__(256) void diff_attn_v5(
    const unsigned short* __restrict__ qkv,   // [B*L][3072] bf16 (Q pre-scaled by log2e/32)
    const unsigned short* __restrict__ vdt,   // [B*H][64][2048] bf16
    const float* __restrict__ lam_p,
    unsigned short* __restrict__ o_ws)        // [B*L][1024] bf16
{
    constexpr int L = 2048, TD = 3072;

    __shared__ unsigned short Ks[2][64][64];  // [seq][dh], chunk-swizzled
    __shared__ unsigned short Vs[2][64][64];  // [dh][seq], chunk-swizzled

    const int tid = threadIdx.x;
    const int wave = tid >> 6, lane = tid & 63;
    const int quad = lane >> 4, ln = lane & 15;
    const int bh = blockIdx.y, b = bh >> 4, h = bh & 15;
    const int q0 = blockIdx.x * 128;
    const size_t seqbase = (size_t)b * L;
    const unsigned short* base = qkv + seqbase * TD + h * 64;
    const unsigned short* kb = base + 1024;
    const unsigned short* vbase = vdt + (size_t)bh * 64 * 2048;

    const int lsl = lane >> 3;
    const int cgl = (lane & 7) ^ lsl;

    // Q fragments (layout serves as MFMA B-operand: n=ln -> q, k=quad*8+u -> d)
    s16x8 qf[2][2];
#pragma unroll
    for (int s = 0; s < 2; ++s) {
        const unsigned short* qrow =
            base + (size_t)(q0 + wave * 32 + s * 16 + ln) * TD;
        qf[s][0] = *(const s16x8*)(qrow + quad * 8);
        qf[s][1] = *(const s16x8*)(qrow + 32 + quad * 8);
    }

    auto stage = [&](int p, int j0) {
        const unsigned short* k0p = kb + (size_t)(j0 + wave * 16 + lsl) * TD + cgl * 8;
        gload16(k0p,                  &Ks[p][wave * 16][0]);
        gload16(k0p + (size_t)8 * TD, &Ks[p][wave * 16 + 8][0]);
        const unsigned short* v0p = vbase + (size_t)(wave * 16 + lsl) * 2048 + j0 + cgl * 8;
        gload16(v0p,            &Vs[p][wave * 16][0]);
        gload16(v0p + 8 * 2048, &Vs[p][wave * 16 + 8][0]);
    };

    f32x4 Ot[2][4];    // O^T accumulators: q=ln, d = mt*16 + quad*4 + rg
    f32x4 lacc[2];     // row-sum accumulators via ones-MFMA (all rg equal)
#pragma unroll
    for (int s = 0; s < 2; ++s) {
        lacc[s] = f32x4{0.f, 0.f, 0.f, 0.f};
#pragma unroll
        for (int mt = 0; mt < 4; ++mt) Ot[s][mt] = f32x4{0.f, 0.f, 0.f, 0.f};
    }

    const s16x4 ones = {(short)0x3F80, (short)0x3F80, (short)0x3F80, (short)0x3F80};
    const int kx0 = (quad ^ (ln & 7)) << 3;
    const int kx1 = ((quad + 4) ^ (ln & 7)) << 3;

    stage(0, 0);
    __syncthreads();
    int p = 0;
    for (int kt = 0; kt < 32; ++kt) {
        if (kt + 1 < 32) stage(p ^ 1, (kt + 1) * 64);

        // ---- S^T = K Q^T: A = K-frag (m=j), B = qf (n=q). C: col=ln->q, row=quad*4+rg->j
        f32x4 ST[2][4];
#pragma unroll
        for (int t = 0; t < 4; ++t) {
            s16x8 k0 = *(const s16x8*)&Ks[p][t * 16 + ln][kx0];
            s16x8 k1 = *(const s16x8*)&Ks[p][t * 16 + ln][kx1];
#pragma unroll
            for (int s = 0; s < 2; ++s) {
                f32x4 z = f32x4{0.f, 0.f, 0.f, 0.f};
                z = __builtin_amdgcn_mfma_f32_16x16x32_bf16(k0, qf[s][0], z, 0, 0, 0);
                z = __builtin_amdgcn_mfma_f32_16x16x32_bf16(k1, qf[s][1], z, 0, 0, 0);
                ST[s][t] = z;
            }
        }

        // ---- P^T = exp2(S^T) packed to bf16 in-register: B-frag of 16x16x16
        //      (k = quad*4+u <-> j = t*16+quad*4+rg: exact match, no data movement)
        s16x4 pf[2][4];
#pragma unroll
        for (int s = 0; s < 2; ++s)
#pragma unroll
            for (int t = 0; t < 4; ++t) {
                unsigned int b0 = __builtin_bit_cast(unsigned int,
                    __builtin_amdgcn_exp2f(ST[s][t][0]));
                unsigned int b1 = __builtin_bit_cast(unsigned int,
                    __builtin_amdgcn_exp2f(ST[s][t][1]));
                unsigned int b2 = __builtin_bit_cast(unsigned int,
                    __builtin_amdgcn_exp2f(ST[s][t][2]));
                unsigned int b3 = __builtin_bit_cast(unsigned int,
                    __builtin_amdgcn_exp2f(ST[s][t][3]));
                unsigned int lo = (b0 >> 16) | (b1 & 0xFFFF0000u);
                unsigned int hi = (b2 >> 16) | (b3 & 0xFFFF0000u);
                uint2 pk = make_uint2(lo, hi);
                pf[s][t] = __builtin_bit_cast(s16x4, pk);
            }

        // ---- row sums l[q] += sum_j P^T[j][q] via ones-MFMA (all C rows equal) ----
#pragma unroll
        for (int s = 0; s < 2; ++s)
#pragma unroll
            for (int t = 0; t < 4; ++t)
                lacc[s] = mfma16(ones, pf[s][t], lacc[s]);

        // ---- O^T += Vd^T P^T: A = Vd^T-frag (m=d, k=j), B = pf ----
#pragma unroll
        for (int t = 0; t < 4; ++t) {
#pragma unroll
            for (int mt = 0; mt < 4; ++mt) {
                int chunk = (2 * t + (quad >> 1)) ^ (ln & 7);
                s16x4 vf = *(const s16x4*)&Vs[p][mt * 16 + ln][chunk * 8 + (quad & 1) * 4];
#pragma unroll
                for (int s = 0; s < 2; ++s)
                    Ot[s][mt] = mfma16(vf, pf[s][t], Ot[s][mt]);
            }
        }
        __syncthreads();
        p ^= 1;
    }

    const float lam = lam_p[0];
#pragma unroll
    for (int s = 0; s < 2; ++s) {
        float inv = lam / lacc[s][0];
        int row = q0 + wave * 32 + s * 16 + ln;
        unsigned short* orow = o_ws + (seqbase + row) * 1024 + h * 64 + quad * 4;
#pragma unroll
        for (int mt = 0; mt < 4; ++mt) {
            ushort4 u;
            u.x = f2bf(Ot[s][mt][0] * inv);
            u.y = f2bf(Ot[s][mt][1] * inv);
            u.z = f2bf(Ot[s][mt][2] * inv);
            u.w = f2bf(Ot[s][mt][3] * inv);
            *(ushort4*)(orow + mt * 16) = u;
        }
    }
}

extern "C" void kernel_launch(void* const* d_in, const int* in_sizes, int n_in,
                              void* d_out, int out_size, void* d_ws, size_t ws_size,
                              hipStream_t stream) {
    const float* x     = (const float*)d_in[0];
    const float* w_qkv = (const float*)d_in[1];
    const float* b_qkv = (const float*)d_in[2];
    const float* w_out = (const float*)d_in[3];
    const float* b_out = (const float*)d_in[4];
    const float* lam   = (const float*)d_in[5];
    float* out = (float*)d_out;

    unsigned short* xb   = (unsigned short*)d_ws;
    unsigned short* wqb  = xb   + (size_t)4096 * 1024;
    unsigned short* wob  = wqb  + (size_t)3072 * 1024;
    unsigned short* qkvb = wob  + (size_t)1024 * 1024;
    unsigned short* ob   = qkvb + (size_t)4096 * 3072;
    unsigned short* vdt  = ob   + (size_t)4096 * 1024;

    cvt_all<<<8192, 256, 0, stream>>>(x, w_qkv, w_out, xb, wqb, wob);

    // qkv = x @ w_qkv^T + b_qkv; Q cols (n<1024) pre-scaled by log2(e)/32
    gemm_nt_mfma<1, 128><<<dim3(24, 32), 256, 0, stream>>>(
        xb, wqb, b_qkv, qkvb, 4096, 3072, 1024, 1024, 0.045084222f);

    vd_transpose<<<dim3(32, 32), 256, 0, stream>>>(qkvb, vdt);

    diff_attn_v5<<<dim3(16, 32), 256, 0, stream>>>(qkvb, vdt, lam, ob);

    gemm_nt_mfma<0, 64><<<dim3(16, 32), 256, 0, stream>>>(
        ob, wob, b_out, out, 4096, 1024, 1024, 0, 1.f);
}